// Round 1
// baseline (1673.613 us; speedup 1.0000x reference)
//
#include <hip/hip_runtime.h>

constexpr int N = 100000;
constexpr int E = 1280000;
constexpr int C = 64;

__global__ void degree_k(const int* __restrict__ dst, float* __restrict__ cnt) {
    int e = blockIdx.x * blockDim.x + threadIdx.x;
    if (e < E) atomicAdd(&cnt[dst[e]], 1.0f);
}

// one thread per (edge, channel): a 64-lane wave covers exactly one edge,
// so both the gather from feat[src] and the atomic burst to agg[dst] are
// contiguous 256B segments.
__global__ void scatter_k(const int* __restrict__ src, const int* __restrict__ dst,
                          const float* __restrict__ feat, float* __restrict__ agg) {
    long long t = (long long)blockIdx.x * blockDim.x + threadIdx.x;
    int e = (int)(t >> 6);
    int c = (int)(t & 63);
    if (e < E) {
        int s = src[e], d = dst[e];
        atomicAdd(&agg[(size_t)d * C + c], feat[(size_t)s * C + c]);
    }
}

// one wave per node; weights staged transposed in LDS so lane c reads
// sW[k*64+c] (consecutive -> 2-way bank aliasing, free on CDNA4).
template <int RELU>
__global__ __launch_bounds__(256) void combine_k(
    const float* __restrict__ agg, const float* __restrict__ cnt,
    const float* __restrict__ xin, const float* __restrict__ Wl,
    const float* __restrict__ bias, const float* __restrict__ Wr,
    float* __restrict__ out) {
    __shared__ float sWl[C * C];
    __shared__ float sWr[C * C];
    __shared__ float sb[C];
    for (int idx = threadIdx.x; idx < C * C; idx += blockDim.x) {
        int c = idx >> 6, k = idx & 63;
        sWl[k * C + c] = Wl[idx];   // transpose: sWl[k][c] = Wl[c][k]
        sWr[k * C + c] = Wr[idx];
    }
    if (threadIdx.x < C) sb[threadIdx.x] = bias[threadIdx.x];
    __syncthreads();

    int wave = threadIdx.x >> 6;
    int lane = threadIdx.x & 63;
    int node = blockIdx.x * 4 + wave;
    if (node >= N) return;

    float cn = cnt[node];
    float inv = cn > 0.f ? 1.f / cn : 0.f;  // isolated nodes: agg==0 anyway
    float av = agg[(size_t)node * C + lane] * inv;
    float xv = xin[(size_t)node * C + lane];
    float acc = sb[lane];
#pragma unroll
    for (int k = 0; k < C; ++k) {
        acc = fmaf(__shfl(av, k), sWl[k * C + lane], acc);
        acc = fmaf(__shfl(xv, k), sWr[k * C + lane], acc);
    }
    if (RELU) acc = fmaxf(acc, 0.f);
    out[(size_t)node * C + lane] = acc;
}

extern "C" void kernel_launch(void* const* d_in, const int* in_sizes, int n_in,
                              void* d_out, int out_size, void* d_ws, size_t ws_size,
                              hipStream_t stream) {
    const float* x   = (const float*)d_in[0];
    const int*   ei  = (const int*)d_in[1];   // [2, E] int32
    const int*   srcI = ei;
    const int*   dstI = ei + E;
    const float* W1l = (const float*)d_in[2];
    const float* b1  = (const float*)d_in[3];
    const float* W1r = (const float*)d_in[4];
    const float* W2l = (const float*)d_in[5];
    const float* b2  = (const float*)d_in[6];
    const float* W2r = (const float*)d_in[7];
    float* out = (float*)d_out;

    float* cnt = (float*)d_ws;
    float* agg = cnt + 131072;                 // 512KB in, 256B-aligned
    float* h   = agg + (size_t)N * C;

    hipMemsetAsync(cnt, 0, (size_t)N * sizeof(float), stream);
    hipMemsetAsync(agg, 0, (size_t)N * C * sizeof(float), stream);

    degree_k<<<(E + 255) / 256, 256, 0, stream>>>(dstI, cnt);

    // ---- layer 1 ----
    scatter_k<<<(int)(((size_t)E * C + 255) / 256), 256, 0, stream>>>(srcI, dstI, x, agg);
    combine_k<1><<<(N + 3) / 4, 256, 0, stream>>>(agg, cnt, x, W1l, b1, W1r, h);

    // ---- layer 2 ----
    hipMemsetAsync(agg, 0, (size_t)N * C * sizeof(float), stream);
    scatter_k<<<(int)(((size_t)E * C + 255) / 256), 256, 0, stream>>>(srcI, dstI, h, agg);
    combine_k<0><<<(N + 3) / 4, 256, 0, stream>>>(agg, cnt, h, W2l, b2, W2r, out);
}

// Round 2
// 733.176 us; speedup vs baseline: 2.2827x; 2.2827x over previous
//
#include <hip/hip_runtime.h>

constexpr int N = 100000;
constexpr int E = 1280000;
constexpr int C = 64;

__global__ void degree_k(const int* __restrict__ dst, float* __restrict__ cnt) {
    int e = blockIdx.x * blockDim.x + threadIdx.x;
    if (e < E) atomicAdd(&cnt[dst[e]], 1.0f);
}

// one thread per (edge, channel): a 64-lane wave covers exactly one edge,
// so both the gather from feat[src] and the atomic burst to agg[dst] are
// contiguous 256B segments.
__global__ void scatter_k(const int* __restrict__ src, const int* __restrict__ dst,
                          const float* __restrict__ feat, float* __restrict__ agg) {
    long long t = (long long)blockIdx.x * blockDim.x + threadIdx.x;
    int e = (int)(t >> 6);
    int c = (int)(t & 63);
    if (e < E) {
        int s = src[e], d = dst[e];
        atomicAdd(&agg[(size_t)d * C + c], feat[(size_t)s * C + c]);
    }
}

// Register-blocked tiled GEMM: out[n][c] = sum_k a[n][k]*Wl[c][k] + x[n][k]*Wr[c][k] + b[c]
// Block: 256 threads, 64-node x 64-ch tile, per-thread 4x4 micro-tile.
// LDS: sA/sX padded +4 floats (row-quad reads -> 2 addrs/bank = free);
// weights stored transposed sW[k][c] so reads span 256B (free 2-way).
template <int RELU>
__global__ __launch_bounds__(256, 2) void combine_k(
    const float* __restrict__ agg, const float* __restrict__ cnt,
    const float* __restrict__ xin, const float* __restrict__ Wl,
    const float* __restrict__ bias, const float* __restrict__ Wr,
    float* __restrict__ out) {
    constexpr int PADC = C + 4;
    __shared__ float sA[64][PADC];
    __shared__ float sX[64][PADC];
    __shared__ float sWl[C][C];   // sWl[k][c]
    __shared__ float sWr[C][C];

    const int t = threadIdx.x;
    const int nodeBase = blockIdx.x * 64;

    // ---- stage weights transposed (one-time 16-way store conflict, negligible) ----
#pragma unroll
    for (int i = 0; i < 4; ++i) {
        int flat = (t + i * 256) * 4;          // 4 consecutive k, fixed c
        int c = flat >> 6, k = flat & 63;
        float4 wl = *(const float4*)(Wl + flat);
        float4 wr = *(const float4*)(Wr + flat);
        sWl[k + 0][c] = wl.x; sWl[k + 1][c] = wl.y; sWl[k + 2][c] = wl.z; sWl[k + 3][c] = wl.w;
        sWr[k + 0][c] = wr.x; sWr[k + 1][c] = wr.y; sWr[k + 2][c] = wr.z; sWr[k + 3][c] = wr.w;
    }

    // ---- stage A (mean-scaled) and X tiles ----
    {
        const int f4 = (t & 15) * 4;
        const int r0 = t >> 4;
#pragma unroll
        for (int r = 0; r < 4; ++r) {
            int n = r0 + r * 16;
            int gn = nodeBase + n;
            float4 av = make_float4(0.f, 0.f, 0.f, 0.f);
            float4 xv = make_float4(0.f, 0.f, 0.f, 0.f);
            float inv = 0.f;
            if (gn < N) {
                float cn = cnt[gn];
                inv = cn > 0.f ? 1.f / cn : 0.f;
                av = *(const float4*)(agg + (size_t)gn * C + f4);
                xv = *(const float4*)(xin + (size_t)gn * C + f4);
            }
            av.x *= inv; av.y *= inv; av.z *= inv; av.w *= inv;
            *(float4*)&sA[n][f4] = av;
            *(float4*)&sX[n][f4] = xv;
        }
    }
    __syncthreads();

    const int c4 = (t & 15) * 4;
    const int n4 = (t >> 4) * 4;

    float acc[4][4];
#pragma unroll
    for (int i = 0; i < 4; ++i)
#pragma unroll
        for (int j = 0; j < 4; ++j) acc[i][j] = 0.f;

    for (int k0 = 0; k0 < C; k0 += 4) {
        float4 a[4], xx[4], wl[4], wr[4];
#pragma unroll
        for (int i = 0; i < 4; ++i) {
            a[i]  = *(const float4*)&sA[n4 + i][k0];
            xx[i] = *(const float4*)&sX[n4 + i][k0];
        }
#pragma unroll
        for (int j = 0; j < 4; ++j) {
            wl[j] = *(const float4*)&sWl[k0 + j][c4];
            wr[j] = *(const float4*)&sWr[k0 + j][c4];
        }
#pragma unroll
        for (int kk = 0; kk < 4; ++kk) {
            const float* wlk = (const float*)&wl[kk];
            const float* wrk = (const float*)&wr[kk];
#pragma unroll
            for (int i = 0; i < 4; ++i) {
                float a_ = ((const float*)&a[i])[kk];
                float x_ = ((const float*)&xx[i])[kk];
#pragma unroll
                for (int j = 0; j < 4; ++j) {
                    acc[i][j] = fmaf(a_, wlk[j], acc[i][j]);
                    acc[i][j] = fmaf(x_, wrk[j], acc[i][j]);
                }
            }
        }
    }

    const float4 bl = *(const float4*)(bias + c4);
    const float* blp = (const float*)&bl;
#pragma unroll
    for (int i = 0; i < 4; ++i) {
        int gn = nodeBase + n4 + i;
        if (gn < N) {
            float4 o;
            float* op = (float*)&o;
#pragma unroll
            for (int j = 0; j < 4; ++j) {
                float v = acc[i][j] + blp[j];
                op[j] = RELU ? fmaxf(v, 0.f) : v;
            }
            *(float4*)(out + (size_t)gn * C + c4) = o;
        }
    }
}

extern "C" void kernel_launch(void* const* d_in, const int* in_sizes, int n_in,
                              void* d_out, int out_size, void* d_ws, size_t ws_size,
                              hipStream_t stream) {
    const float* x   = (const float*)d_in[0];
    const int*   ei  = (const int*)d_in[1];   // [2, E] int32
    const int*   srcI = ei;
    const int*   dstI = ei + E;
    const float* W1l = (const float*)d_in[2];
    const float* b1  = (const float*)d_in[3];
    const float* W1r = (const float*)d_in[4];
    const float* W2l = (const float*)d_in[5];
    const float* b2  = (const float*)d_in[6];
    const float* W2r = (const float*)d_in[7];
    float* out = (float*)d_out;

    float* cnt = (float*)d_ws;
    float* agg = cnt + 131072;                 // 512KB in, 256B-aligned
    float* h   = agg + (size_t)N * C;

    hipMemsetAsync(cnt, 0, (size_t)N * sizeof(float), stream);
    hipMemsetAsync(agg, 0, (size_t)N * C * sizeof(float), stream);

    degree_k<<<(E + 255) / 256, 256, 0, stream>>>(dstI, cnt);

    const int nCombineBlocks = (N + 63) / 64;

    // ---- layer 1 ----
    scatter_k<<<(int)(((size_t)E * C + 255) / 256), 256, 0, stream>>>(srcI, dstI, x, agg);
    combine_k<1><<<nCombineBlocks, 256, 0, stream>>>(agg, cnt, x, W1l, b1, W1r, h);

    // ---- layer 2 ----
    hipMemsetAsync(agg, 0, (size_t)N * C * sizeof(float), stream);
    scatter_k<<<(int)(((size_t)E * C + 255) / 256), 256, 0, stream>>>(srcI, dstI, h, agg);
    combine_k<0><<<nCombineBlocks, 256, 0, stream>>>(agg, cnt, h, W2l, b2, W2r, out);
}

// Round 3
// 341.955 us; speedup vs baseline: 4.8943x; 2.1441x over previous
//
#include <hip/hip_runtime.h>

constexpr int N = 100000;
constexpr int E = 1280000;
constexpr int C = 64;

// ---------------- CSR build ----------------

__global__ void hist_k(const int* __restrict__ dst, int* __restrict__ deg) {
    int e = blockIdx.x * blockDim.x + threadIdx.x;
    if (e < E) atomicAdd(&deg[dst[e]], 1);
}

// per-256-block exclusive scan; block totals to bsum
__global__ __launch_bounds__(256) void scan1_k(const int* __restrict__ deg,
                                               int* __restrict__ rowp,
                                               int* __restrict__ bsum) {
    __shared__ int s[2][256];
    int t = threadIdx.x;
    int i = blockIdx.x * 256 + t;
    int v = (i < N) ? deg[i] : 0;
    int p = 0;
    s[0][t] = v;
    __syncthreads();
    for (int off = 1; off < 256; off <<= 1) {
        s[p ^ 1][t] = s[p][t] + (t >= off ? s[p][t - off] : 0);
        p ^= 1;
        __syncthreads();
    }
    int incl = s[p][t];
    if (i < N) rowp[i] = incl - v;
    if (t == 255) bsum[blockIdx.x] = incl;
}

// single-block exclusive scan of block sums (nb <= 512)
__global__ __launch_bounds__(512) void scan2_k(int* __restrict__ bsum, int nb) {
    __shared__ int s[2][512];
    int t = threadIdx.x;
    int v = (t < nb) ? bsum[t] : 0;
    int p = 0;
    s[0][t] = v;
    __syncthreads();
    for (int off = 1; off < 512; off <<= 1) {
        s[p ^ 1][t] = s[p][t] + (t >= off ? s[p][t - off] : 0);
        p ^= 1;
        __syncthreads();
    }
    if (t < nb) bsum[t] = s[p][t] - v;
}

__global__ void add_k(int* __restrict__ rowp, const int* __restrict__ bsum) {
    int i = blockIdx.x * 256 + threadIdx.x;
    if (i < N) rowp[i] += bsum[blockIdx.x];
}

__global__ void fill_k(const int* __restrict__ src, const int* __restrict__ dst,
                       const int* __restrict__ rowp, int* __restrict__ cursor,
                       int* __restrict__ csr) {
    int e = blockIdx.x * blockDim.x + threadIdx.x;
    if (e < E) {
        int d = dst[e];
        int pos = rowp[d] + atomicAdd(&cursor[d], 1);
        csr[pos] = src[e];
    }
}

// ---------------- aggregation: one wave per node, lane = channel ----------------
__global__ __launch_bounds__(256) void agg_k(const int* __restrict__ csr,
                                             const int* __restrict__ rowp,
                                             const int* __restrict__ deg,
                                             const float* __restrict__ feat,
                                             float* __restrict__ agg) {
    int node = blockIdx.x * 4 + (threadIdx.x >> 6);
    int lane = threadIdx.x & 63;
    int start = rowp[node];
    int d = deg[node];
    float acc = 0.f;
    int j = 0;
    for (; j + 4 <= d; j += 4) {
        int s0 = csr[start + j + 0];
        int s1 = csr[start + j + 1];
        int s2 = csr[start + j + 2];
        int s3 = csr[start + j + 3];
        float f0 = feat[(size_t)s0 * C + lane];
        float f1 = feat[(size_t)s1 * C + lane];
        float f2 = feat[(size_t)s2 * C + lane];
        float f3 = feat[(size_t)s3 * C + lane];
        acc += (f0 + f1) + (f2 + f3);
    }
    for (; j < d; ++j) acc += feat[(size_t)csr[start + j] * C + lane];
    agg[(size_t)node * C + lane] = d > 0 ? acc / (float)d : 0.f;
}

// ---------------- combine: tiled register-blocked GEMM ----------------
template <int RELU>
__global__ __launch_bounds__(256, 2) void combine_k(
    const float* __restrict__ agg, const float* __restrict__ xin,
    const float* __restrict__ Wl, const float* __restrict__ bias,
    const float* __restrict__ Wr, float* __restrict__ out) {
    constexpr int PADC = C + 4;
    __shared__ float sA[64][PADC];
    __shared__ float sX[64][PADC];
    __shared__ float sWl[C][C];   // sWl[k][c]
    __shared__ float sWr[C][C];

    const int t = threadIdx.x;
    const int nodeBase = blockIdx.x * 64;

#pragma unroll
    for (int i = 0; i < 4; ++i) {
        int flat = (t + i * 256) * 4;          // 4 consecutive k, fixed c
        int c = flat >> 6, k = flat & 63;
        float4 wl = *(const float4*)(Wl + flat);
        float4 wr = *(const float4*)(Wr + flat);
        sWl[k + 0][c] = wl.x; sWl[k + 1][c] = wl.y; sWl[k + 2][c] = wl.z; sWl[k + 3][c] = wl.w;
        sWr[k + 0][c] = wr.x; sWr[k + 1][c] = wr.y; sWr[k + 2][c] = wr.z; sWr[k + 3][c] = wr.w;
    }

    {
        const int f4 = (t & 15) * 4;
        const int r0 = t >> 4;
#pragma unroll
        for (int r = 0; r < 4; ++r) {
            int n = r0 + r * 16;
            int gn = nodeBase + n;
            float4 av = make_float4(0.f, 0.f, 0.f, 0.f);
            float4 xv = make_float4(0.f, 0.f, 0.f, 0.f);
            if (gn < N) {
                av = *(const float4*)(agg + (size_t)gn * C + f4);
                xv = *(const float4*)(xin + (size_t)gn * C + f4);
            }
            *(float4*)&sA[n][f4] = av;
            *(float4*)&sX[n][f4] = xv;
        }
    }
    __syncthreads();

    const int c4 = (t & 15) * 4;
    const int n4 = (t >> 4) * 4;

    float acc[4][4];
#pragma unroll
    for (int i = 0; i < 4; ++i)
#pragma unroll
        for (int j = 0; j < 4; ++j) acc[i][j] = 0.f;

    for (int k0 = 0; k0 < C; k0 += 4) {
        float4 a[4], xx[4], wl[4], wr[4];
#pragma unroll
        for (int i = 0; i < 4; ++i) {
            a[i]  = *(const float4*)&sA[n4 + i][k0];
            xx[i] = *(const float4*)&sX[n4 + i][k0];
        }
#pragma unroll
        for (int j = 0; j < 4; ++j) {
            wl[j] = *(const float4*)&sWl[k0 + j][c4];
            wr[j] = *(const float4*)&sWr[k0 + j][c4];
        }
#pragma unroll
        for (int kk = 0; kk < 4; ++kk) {
            const float* wlk = (const float*)&wl[kk];
            const float* wrk = (const float*)&wr[kk];
#pragma unroll
            for (int i = 0; i < 4; ++i) {
                float a_ = ((const float*)&a[i])[kk];
                float x_ = ((const float*)&xx[i])[kk];
#pragma unroll
                for (int j = 0; j < 4; ++j) {
                    acc[i][j] = fmaf(a_, wlk[j], acc[i][j]);
                    acc[i][j] = fmaf(x_, wrk[j], acc[i][j]);
                }
            }
        }
    }

    const float4 bl = *(const float4*)(bias + c4);
    const float* blp = (const float*)&bl;
#pragma unroll
    for (int i = 0; i < 4; ++i) {
        int gn = nodeBase + n4 + i;
        if (gn < N) {
            float4 o;
            float* op = (float*)&o;
#pragma unroll
            for (int j = 0; j < 4; ++j) {
                float v = acc[i][j] + blp[j];
                op[j] = RELU ? fmaxf(v, 0.f) : v;
            }
            *(float4*)(out + (size_t)gn * C + c4) = o;
        }
    }
}

extern "C" void kernel_launch(void* const* d_in, const int* in_sizes, int n_in,
                              void* d_out, int out_size, void* d_ws, size_t ws_size,
                              hipStream_t stream) {
    const float* x   = (const float*)d_in[0];
    const int*   ei  = (const int*)d_in[1];   // [2, E] int32
    const int*   srcI = ei;
    const int*   dstI = ei + E;
    const float* W1l = (const float*)d_in[2];
    const float* b1  = (const float*)d_in[3];
    const float* W1r = (const float*)d_in[4];
    const float* W2l = (const float*)d_in[5];
    const float* b2  = (const float*)d_in[6];
    const float* W2r = (const float*)d_in[7];
    float* out = (float*)d_out;

    // workspace layout (4B elements)
    int*   deg    = (int*)d_ws;                 // N (padded 131072)
    int*   rowp   = deg + 131072;               // N
    int*   cursor = rowp + 131072;              // N
    int*   bsum   = cursor + 131072;            // 512
    int*   csr    = bsum + 512;                 // E
    float* agg    = (float*)(csr + E);          // N*C
    float* h      = agg + (size_t)N * C;        // N*C

    const int nbScan = (N + 255) / 256;         // 391

    hipMemsetAsync(deg, 0, 131072 * sizeof(int), stream);
    hipMemsetAsync(cursor, 0, 131072 * sizeof(int), stream);

    hist_k<<<(E + 255) / 256, 256, 0, stream>>>(dstI, deg);
    scan1_k<<<nbScan, 256, 0, stream>>>(deg, rowp, bsum);
    scan2_k<<<1, 512, 0, stream>>>(bsum, nbScan);
    add_k<<<nbScan, 256, 0, stream>>>(rowp, bsum);
    fill_k<<<(E + 255) / 256, 256, 0, stream>>>(srcI, dstI, rowp, cursor, csr);

    const int nCombineBlocks = (N + 63) / 64;
    const int nAggBlocks = N / 4;               // 25000, exact

    // ---- layer 1 ----
    agg_k<<<nAggBlocks, 256, 0, stream>>>(csr, rowp, deg, x, agg);
    combine_k<1><<<nCombineBlocks, 256, 0, stream>>>(agg, x, W1l, b1, W1r, h);

    // ---- layer 2 ----
    agg_k<<<nAggBlocks, 256, 0, stream>>>(csr, rowp, deg, h, agg);
    combine_k<0><<<nCombineBlocks, 256, 0, stream>>>(agg, h, W2l, b2, W2r, out);
}

// Round 4
// 245.974 us; speedup vs baseline: 6.8040x; 1.3902x over previous
//
#include <hip/hip_runtime.h>

constexpr int N = 100000;
constexpr int E = 1280000;
constexpr int C = 64;
constexpr int NB = (N + 255) / 256;   // 391 dst-buckets of 256 nodes
constexpr int EPB = 4096;             // edges per bin_k block
constexpr int NBIN = (E + EPB - 1) / EPB;  // 313
constexpr int CAP = 8192;             // bucket capacity (avg 3274, max ~3.6k)

// ---------------- stage 0: coarse histogram of dst>>8 ----------------
__global__ __launch_bounds__(256) void chist_k(const int* __restrict__ dst,
                                               int* __restrict__ bcnt) {
    __shared__ int h[NB];
    int t = threadIdx.x;
    for (int i = t; i < NB; i += 256) h[i] = 0;
    __syncthreads();
    int e0 = blockIdx.x * EPB;
    int eEnd = min(e0 + EPB, E);
    for (int e = e0 + t; e < eEnd; e += 256) atomicAdd(&h[dst[e] >> 8], 1);
    __syncthreads();
    for (int i = t; i < NB; i += 256)
        if (h[i]) atomicAdd(&bcnt[i], h[i]);
}

// ---------------- stage 1: scan bucket counts -> bases; zero cursors ----------------
__global__ __launch_bounds__(512) void scanB_k(const int* __restrict__ bcnt,
                                               int* __restrict__ bbase,
                                               int* __restrict__ gcur) {
    __shared__ int s[2][512];
    int t = threadIdx.x;
    int v = (t < NB) ? bcnt[t] : 0;
    s[0][t] = v;
    __syncthreads();
    int p = 0;
    for (int off = 1; off < 512; off <<= 1) {
        int a = s[p][t] + (t >= off ? s[p][t - off] : 0);
        s[p ^ 1][t] = a;
        p ^= 1;
        __syncthreads();
    }
    if (t < NB) { bbase[t] = s[p][t] - v; gcur[t] = 0; }
}

// ---------------- stage 2: bin edges into bucket-contiguous pair runs ----------------
__global__ __launch_bounds__(256) void bin_k(const int* __restrict__ src,
                                             const int* __restrict__ dst,
                                             const int* __restrict__ bbase,
                                             int* __restrict__ gcur,
                                             uint2* __restrict__ tmp) {
    __shared__ int hist[NB];
    __shared__ int start[NB];
    __shared__ int cnt2[NB];
    __shared__ int gbase[NB];
    __shared__ uint2 pairs[EPB];     // 32 KB
    __shared__ int sc[2][512];
    int t = threadIdx.x;
    for (int i = t; i < NB; i += 256) { hist[i] = 0; cnt2[i] = 0; }
    __syncthreads();
    int e0 = blockIdx.x * EPB;
    int eEnd = min(e0 + EPB, E);
    for (int e = e0 + t; e < eEnd; e += 256) atomicAdd(&hist[dst[e] >> 8], 1);
    __syncthreads();
    // 512-slot exclusive scan of hist (256 threads, 2 slots each, double-buffer)
    sc[0][t]       = (t < NB) ? hist[t] : 0;
    sc[0][t + 256] = (t + 256 < NB) ? hist[t + 256] : 0;
    __syncthreads();
    int p = 0;
    for (int off = 1; off < 512; off <<= 1) {
        int a = sc[p][t]       + (t >= off ? sc[p][t - off] : 0);
        int b = sc[p][t + 256] + sc[p][t + 256 - off];   // t+256-off >= 0 always
        sc[p ^ 1][t] = a;
        sc[p ^ 1][t + 256] = b;
        p ^= 1;
        __syncthreads();
    }
    if (t < NB)       start[t]       = sc[p][t]       - hist[t];
    if (t + 256 < NB) start[t + 256] = sc[p][t + 256] - hist[t + 256];
    __syncthreads();
    // place pairs into LDS, bucket-sorted
    for (int e = e0 + t; e < eEnd; e += 256) {
        int d = dst[e];
        int b = d >> 8;
        int pos = start[b] + atomicAdd(&cnt2[b], 1);
        pairs[pos] = make_uint2((unsigned)src[e], (unsigned)d);
    }
    __syncthreads();
    // reserve global space: one cursor bump per (block,bucket)
    for (int i = t; i < NB; i += 256)
        gbase[i] = hist[i] ? bbase[i] + atomicAdd(&gcur[i], hist[i]) : 0;
    __syncthreads();
    // flush: contiguous per-bucket runs -> mostly line-merged writes
    int n = eEnd - e0;
    for (int i = t; i < n; i += 256) {
        uint2 pr = pairs[i];
        int b = (int)(pr.y >> 8);
        tmp[gbase[b] + (i - start[b])] = pr;
    }
}

// ---------------- stage 3: per-bucket counting sort -> rowp/deg/csr ----------------
__global__ __launch_bounds__(256) void bsort_k(const uint2* __restrict__ tmp,
                                               const int* __restrict__ bbase,
                                               const int* __restrict__ bcnt,
                                               int* __restrict__ rowp,
                                               int* __restrict__ deg,
                                               int* __restrict__ csr) {
    int b = blockIdx.x;
    int base = bbase[b];
    int count = bcnt[b];
    __shared__ int h[256], st[256], c2[256];
    __shared__ int sc[2][256];
    __shared__ unsigned srcA[CAP];   // 32 KB
    int t = threadIdx.x;
    h[t] = 0; c2[t] = 0;
    __syncthreads();
    for (int i = t; i < count; i += 256) atomicAdd(&h[tmp[base + i].y & 255], 1);
    __syncthreads();
    sc[0][t] = h[t];
    __syncthreads();
    int p = 0;
    for (int off = 1; off < 256; off <<= 1) {
        int a = sc[p][t] + (t >= off ? sc[p][t - off] : 0);
        sc[p ^ 1][t] = a;
        p ^= 1;
        __syncthreads();
    }
    int excl = sc[p][t] - h[t];
    st[t] = excl;
    int node = b * 256 + t;
    if (node < N) { rowp[node] = base + excl; deg[node] = h[t]; }
    __syncthreads();
    for (int i = t; i < count; i += 256) {
        uint2 pr = tmp[base + i];
        int d = pr.y & 255;
        int pos = st[d] + atomicAdd(&c2[d], 1);
        srcA[pos] = pr.x;
    }
    __syncthreads();
    for (int i = t; i < count; i += 256) csr[base + i] = (int)srcA[i];
}

// ---------------- aggregation: one wave per node, lane = channel ----------------
__global__ __launch_bounds__(256) void agg_k(const int* __restrict__ csr,
                                             const int* __restrict__ rowp,
                                             const int* __restrict__ deg,
                                             const float* __restrict__ feat,
                                             float* __restrict__ agg) {
    int node = blockIdx.x * 4 + (threadIdx.x >> 6);
    int lane = threadIdx.x & 63;
    int start = rowp[node];
    int d = deg[node];
    float acc = 0.f;
    int j = 0;
    for (; j + 4 <= d; j += 4) {
        int s0 = csr[start + j + 0];
        int s1 = csr[start + j + 1];
        int s2 = csr[start + j + 2];
        int s3 = csr[start + j + 3];
        float f0 = feat[(size_t)s0 * C + lane];
        float f1 = feat[(size_t)s1 * C + lane];
        float f2 = feat[(size_t)s2 * C + lane];
        float f3 = feat[(size_t)s3 * C + lane];
        acc += (f0 + f1) + (f2 + f3);
    }
    for (; j < d; ++j) acc += feat[(size_t)csr[start + j] * C + lane];
    agg[(size_t)node * C + lane] = d > 0 ? acc / (float)d : 0.f;
}

// ---------------- combine: tiled register-blocked GEMM ----------------
template <int RELU>
__global__ __launch_bounds__(256, 2) void combine_k(
    const float* __restrict__ agg, const float* __restrict__ xin,
    const float* __restrict__ Wl, const float* __restrict__ bias,
    const float* __restrict__ Wr, float* __restrict__ out) {
    constexpr int PADC = C + 4;
    __shared__ float sA[64][PADC];
    __shared__ float sX[64][PADC];
    __shared__ float sWl[C][C];   // sWl[k][c]
    __shared__ float sWr[C][C];

    const int t = threadIdx.x;
    const int nodeBase = blockIdx.x * 64;

#pragma unroll
    for (int i = 0; i < 4; ++i) {
        int flat = (t + i * 256) * 4;          // 4 consecutive k, fixed c
        int c = flat >> 6, k = flat & 63;
        float4 wl = *(const float4*)(Wl + flat);
        float4 wr = *(const float4*)(Wr + flat);
        sWl[k + 0][c] = wl.x; sWl[k + 1][c] = wl.y; sWl[k + 2][c] = wl.z; sWl[k + 3][c] = wl.w;
        sWr[k + 0][c] = wr.x; sWr[k + 1][c] = wr.y; sWr[k + 2][c] = wr.z; sWr[k + 3][c] = wr.w;
    }

    {
        const int f4 = (t & 15) * 4;
        const int r0 = t >> 4;
#pragma unroll
        for (int r = 0; r < 4; ++r) {
            int n = r0 + r * 16;
            int gn = nodeBase + n;
            float4 av = make_float4(0.f, 0.f, 0.f, 0.f);
            float4 xv = make_float4(0.f, 0.f, 0.f, 0.f);
            if (gn < N) {
                av = *(const float4*)(agg + (size_t)gn * C + f4);
                xv = *(const float4*)(xin + (size_t)gn * C + f4);
            }
            *(float4*)&sA[n][f4] = av;
            *(float4*)&sX[n][f4] = xv;
        }
    }
    __syncthreads();

    const int c4 = (t & 15) * 4;
    const int n4 = (t >> 4) * 4;

    float acc[4][4];
#pragma unroll
    for (int i = 0; i < 4; ++i)
#pragma unroll
        for (int j = 0; j < 4; ++j) acc[i][j] = 0.f;

    for (int k0 = 0; k0 < C; k0 += 4) {
        float4 a[4], xx[4], wl[4], wr[4];
#pragma unroll
        for (int i = 0; i < 4; ++i) {
            a[i]  = *(const float4*)&sA[n4 + i][k0];
            xx[i] = *(const float4*)&sX[n4 + i][k0];
        }
#pragma unroll
        for (int j = 0; j < 4; ++j) {
            wl[j] = *(const float4*)&sWl[k0 + j][c4];
            wr[j] = *(const float4*)&sWr[k0 + j][c4];
        }
#pragma unroll
        for (int kk = 0; kk < 4; ++kk) {
            const float* wlk = (const float*)&wl[kk];
            const float* wrk = (const float*)&wr[kk];
#pragma unroll
            for (int i = 0; i < 4; ++i) {
                float a_ = ((const float*)&a[i])[kk];
                float x_ = ((const float*)&xx[i])[kk];
#pragma unroll
                for (int j = 0; j < 4; ++j) {
                    acc[i][j] = fmaf(a_, wlk[j], acc[i][j]);
                    acc[i][j] = fmaf(x_, wrk[j], acc[i][j]);
                }
            }
        }
    }

    const float4 bl = *(const float4*)(bias + c4);
    const float* blp = (const float*)&bl;
#pragma unroll
    for (int i = 0; i < 4; ++i) {
        int gn = nodeBase + n4 + i;
        if (gn < N) {
            float4 o;
            float* op = (float*)&o;
#pragma unroll
            for (int j = 0; j < 4; ++j) {
                float v = acc[i][j] + blp[j];
                op[j] = RELU ? fmaxf(v, 0.f) : v;
            }
            *(float4*)(out + (size_t)gn * C + c4) = o;
        }
    }
}

extern "C" void kernel_launch(void* const* d_in, const int* in_sizes, int n_in,
                              void* d_out, int out_size, void* d_ws, size_t ws_size,
                              hipStream_t stream) {
    const float* x   = (const float*)d_in[0];
    const int*   ei  = (const int*)d_in[1];   // [2, E] int32
    const int*   srcI = ei;
    const int*   dstI = ei + E;
    const float* W1l = (const float*)d_in[2];
    const float* b1  = (const float*)d_in[3];
    const float* W1r = (const float*)d_in[4];
    const float* W2l = (const float*)d_in[5];
    const float* b2  = (const float*)d_in[6];
    const float* W2r = (const float*)d_in[7];
    float* out = (float*)d_out;

    // workspace layout (ints unless noted)
    int*   bcnt  = (int*)d_ws;                  // 512
    int*   bbase = bcnt + 512;                  // 512
    int*   gcur  = bbase + 512;                 // 512
    int*   deg   = gcur + 512;                  // 102400
    int*   rowp  = deg + 102400;                // 102400
    int*   csr   = rowp + 102400;               // E
    float* agg   = (float*)(csr + E);           // N*C floats
    float* h     = agg + (size_t)N * C;         // N*C floats
    // tmp pair storage overlays agg (10.24 MB <= 25.6 MB; agg written later)
    uint2* tmp   = (uint2*)agg;

    hipMemsetAsync(bcnt, 0, 512 * sizeof(int), stream);

    chist_k<<<NBIN, 256, 0, stream>>>(dstI, bcnt);
    scanB_k<<<1, 512, 0, stream>>>(bcnt, bbase, gcur);
    bin_k<<<NBIN, 256, 0, stream>>>(srcI, dstI, bbase, gcur, tmp);
    bsort_k<<<NB, 256, 0, stream>>>(tmp, bbase, bcnt, rowp, deg, csr);

    const int nCombineBlocks = (N + 63) / 64;
    const int nAggBlocks = N / 4;               // 25000, exact

    // ---- layer 1 ----
    agg_k<<<nAggBlocks, 256, 0, stream>>>(csr, rowp, deg, x, agg);
    combine_k<1><<<nCombineBlocks, 256, 0, stream>>>(agg, x, W1l, b1, W1r, h);

    // ---- layer 2 ----
    agg_k<<<nAggBlocks, 256, 0, stream>>>(csr, rowp, deg, h, agg);
    combine_k<0><<<nCombineBlocks, 256, 0, stream>>>(agg, h, W2l, b2, W2r, out);
}

// Round 5
// 225.951 us; speedup vs baseline: 7.4070x; 1.0886x over previous
//
#include <hip/hip_runtime.h>

constexpr int N = 100000;
constexpr int E = 1280000;
constexpr int C = 64;
constexpr int NB = (N + 255) / 256;   // 391 dst-buckets of 256 nodes
constexpr int EPB = 4096;             // edges per bin_k block
constexpr int NBIN = (E + EPB - 1) / EPB;  // 313
constexpr int CAP = 4096;             // bucket capacity (avg 3274, max ~3.6k, 14-sigma safe)

// ---------------- stage 0: coarse histogram of dst>>8 ----------------
__global__ __launch_bounds__(256) void chist_k(const int* __restrict__ dst,
                                               int* __restrict__ bcnt) {
    __shared__ int h[NB];
    int t = threadIdx.x;
    for (int i = t; i < NB; i += 256) h[i] = 0;
    __syncthreads();
    int e0 = blockIdx.x * EPB;
    int eEnd = min(e0 + EPB, E);
    for (int e = e0 + t; e < eEnd; e += 256) atomicAdd(&h[dst[e] >> 8], 1);
    __syncthreads();
    for (int i = t; i < NB; i += 256)
        if (h[i]) atomicAdd(&bcnt[i], h[i]);
}

// ---------------- stage 1: scan bucket counts -> bases; zero cursors ----------------
__global__ __launch_bounds__(512) void scanB_k(const int* __restrict__ bcnt,
                                               int* __restrict__ bbase,
                                               int* __restrict__ gcur) {
    __shared__ int s[2][512];
    int t = threadIdx.x;
    int v = (t < NB) ? bcnt[t] : 0;
    s[0][t] = v;
    __syncthreads();
    int p = 0;
    for (int off = 1; off < 512; off <<= 1) {
        int a = s[p][t] + (t >= off ? s[p][t - off] : 0);
        s[p ^ 1][t] = a;
        p ^= 1;
        __syncthreads();
    }
    if (t < NB) { bbase[t] = s[p][t] - v; gcur[t] = 0; }
}

// ---------------- stage 2: bin edges into bucket-contiguous packed runs ----------------
// packed tmp entry: (src << 8) | (dst & 255)    [src < 2^17 fits bits 8..24]
__global__ __launch_bounds__(256) void bin_k(const int* __restrict__ src,
                                             const int* __restrict__ dst,
                                             const int* __restrict__ bbase,
                                             int* __restrict__ gcur,
                                             unsigned* __restrict__ tmp) {
    __shared__ int hist[NB];
    __shared__ int start[NB];
    __shared__ int cnt2[NB];
    __shared__ int gbase[NB];
    __shared__ unsigned pk[EPB];          // 16 KB packed entries
    __shared__ unsigned short bkt[EPB];   // 8 KB bucket id per slot
    __shared__ int sc[2][512];
    int t = threadIdx.x;
    for (int i = t; i < NB; i += 256) { hist[i] = 0; cnt2[i] = 0; }
    __syncthreads();
    int e0 = blockIdx.x * EPB;
    int eEnd = min(e0 + EPB, E);
    for (int e = e0 + t; e < eEnd; e += 256) atomicAdd(&hist[dst[e] >> 8], 1);
    __syncthreads();
    sc[0][t]       = (t < NB) ? hist[t] : 0;
    sc[0][t + 256] = (t + 256 < NB) ? hist[t + 256] : 0;
    __syncthreads();
    int p = 0;
    for (int off = 1; off < 512; off <<= 1) {
        int a = sc[p][t]       + (t >= off ? sc[p][t - off] : 0);
        int b = sc[p][t + 256] + sc[p][t + 256 - off];
        sc[p ^ 1][t] = a;
        sc[p ^ 1][t + 256] = b;
        p ^= 1;
        __syncthreads();
    }
    if (t < NB)       start[t]       = sc[p][t]       - hist[t];
    if (t + 256 < NB) start[t + 256] = sc[p][t + 256] - hist[t + 256];
    __syncthreads();
    for (int e = e0 + t; e < eEnd; e += 256) {
        int d = dst[e];
        int b = d >> 8;
        int pos = start[b] + atomicAdd(&cnt2[b], 1);
        pk[pos] = ((unsigned)src[e] << 8) | (unsigned)(d & 255);
        bkt[pos] = (unsigned short)b;
    }
    __syncthreads();
    for (int i = t; i < NB; i += 256)
        gbase[i] = hist[i] ? bbase[i] + atomicAdd(&gcur[i], hist[i]) : 0;
    __syncthreads();
    int n = eEnd - e0;
    for (int i = t; i < n; i += 256) {
        int b = bkt[i];
        tmp[gbase[b] + (i - start[b])] = pk[i];
    }
}

// ---------------- stage 3: per-bucket counting sort -> rowp/deg/csr ----------------
__global__ __launch_bounds__(256) void bsort_k(const unsigned* __restrict__ tmp,
                                               const int* __restrict__ bbase,
                                               const int* __restrict__ bcnt,
                                               int* __restrict__ rowp,
                                               int* __restrict__ deg,
                                               int* __restrict__ csr) {
    int b = blockIdx.x;
    int base = bbase[b];
    int count = bcnt[b];
    __shared__ int h[256], st[256], c2[256];
    __shared__ int sc[2][256];
    __shared__ unsigned srcA[CAP];   // 16 KB
    int t = threadIdx.x;
    h[t] = 0; c2[t] = 0;
    __syncthreads();
    for (int i = t; i < count; i += 256) atomicAdd(&h[tmp[base + i] & 255u], 1);
    __syncthreads();
    sc[0][t] = h[t];
    __syncthreads();
    int p = 0;
    for (int off = 1; off < 256; off <<= 1) {
        int a = sc[p][t] + (t >= off ? sc[p][t - off] : 0);
        sc[p ^ 1][t] = a;
        p ^= 1;
        __syncthreads();
    }
    int excl = sc[p][t] - h[t];
    st[t] = excl;
    int node = b * 256 + t;
    if (node < N) { rowp[node] = base + excl; deg[node] = h[t]; }
    __syncthreads();
    for (int i = t; i < count; i += 256) {
        unsigned pr = tmp[base + i];
        int d = (int)(pr & 255u);
        int pos = st[d] + atomicAdd(&c2[d], 1);
        srcA[pos] = pr >> 8;
    }
    __syncthreads();
    for (int i = t; i < count; i += 256) csr[base + i] = (int)srcA[i];
}

// ---------------- aggregation: one wave per node, 4 edge-groups x float4 lanes ----------------
__global__ __launch_bounds__(256) void agg_k(const int* __restrict__ csr,
                                             const int* __restrict__ rowp,
                                             const int* __restrict__ deg,
                                             const float* __restrict__ feat,
                                             float* __restrict__ agg) {
    int node = blockIdx.x * 4 + (threadIdx.x >> 6);
    int lane = threadIdx.x & 63;
    int g = lane >> 4;            // edge group 0..3
    int c4 = (lane & 15) * 4;     // channel quad
    int start = rowp[node];
    int d = deg[node];
    float4 acc = make_float4(0.f, 0.f, 0.f, 0.f);
    int j = g;
    for (; j + 4 < d; j += 8) {   // 2-deep unroll: 8 edges in flight per wave
        int s0 = csr[start + j];
        int s1 = csr[start + j + 4];
        float4 f0 = *(const float4*)(feat + (size_t)s0 * C + c4);
        float4 f1 = *(const float4*)(feat + (size_t)s1 * C + c4);
        acc.x += f0.x + f1.x; acc.y += f0.y + f1.y;
        acc.z += f0.z + f1.z; acc.w += f0.w + f1.w;
    }
    for (; j < d; j += 4) {
        int s0 = csr[start + j];
        float4 f0 = *(const float4*)(feat + (size_t)s0 * C + c4);
        acc.x += f0.x; acc.y += f0.y; acc.z += f0.z; acc.w += f0.w;
    }
#pragma unroll
    for (int off = 16; off <= 32; off <<= 1) {
        acc.x += __shfl_xor(acc.x, off);
        acc.y += __shfl_xor(acc.y, off);
        acc.z += __shfl_xor(acc.z, off);
        acc.w += __shfl_xor(acc.w, off);
    }
    if (g == 0) {
        float inv = d > 0 ? 1.f / (float)d : 0.f;
        acc.x *= inv; acc.y *= inv; acc.z *= inv; acc.w *= inv;
        *(float4*)(agg + (size_t)node * C + c4) = acc;
    }
}

// ---------------- combine: tiled register-blocked GEMM ----------------
template <int RELU>
__global__ __launch_bounds__(256, 2) void combine_k(
    const float* __restrict__ agg, const float* __restrict__ xin,
    const float* __restrict__ Wl, const float* __restrict__ bias,
    const float* __restrict__ Wr, float* __restrict__ out) {
    constexpr int PADC = C + 4;
    __shared__ float sA[64][PADC];
    __shared__ float sX[64][PADC];
    __shared__ float sWl[C][C];
    __shared__ float sWr[C][C];

    const int t = threadIdx.x;
    const int nodeBase = blockIdx.x * 64;

#pragma unroll
    for (int i = 0; i < 4; ++i) {
        int flat = (t + i * 256) * 4;
        int c = flat >> 6, k = flat & 63;
        float4 wl = *(const float4*)(Wl + flat);
        float4 wr = *(const float4*)(Wr + flat);
        sWl[k + 0][c] = wl.x; sWl[k + 1][c] = wl.y; sWl[k + 2][c] = wl.z; sWl[k + 3][c] = wl.w;
        sWr[k + 0][c] = wr.x; sWr[k + 1][c] = wr.y; sWr[k + 2][c] = wr.z; sWr[k + 3][c] = wr.w;
    }

    {
        const int f4 = (t & 15) * 4;
        const int r0 = t >> 4;
#pragma unroll
        for (int r = 0; r < 4; ++r) {
            int n = r0 + r * 16;
            int gn = nodeBase + n;
            float4 av = make_float4(0.f, 0.f, 0.f, 0.f);
            float4 xv = make_float4(0.f, 0.f, 0.f, 0.f);
            if (gn < N) {
                av = *(const float4*)(agg + (size_t)gn * C + f4);
                xv = *(const float4*)(xin + (size_t)gn * C + f4);
            }
            *(float4*)&sA[n][f4] = av;
            *(float4*)&sX[n][f4] = xv;
        }
    }
    __syncthreads();

    const int c4 = (t & 15) * 4;
    const int n4 = (t >> 4) * 4;

    float acc[4][4];
#pragma unroll
    for (int i = 0; i < 4; ++i)
#pragma unroll
        for (int j = 0; j < 4; ++j) acc[i][j] = 0.f;

    for (int k0 = 0; k0 < C; k0 += 4) {
        float4 a[4], xx[4], wl[4], wr[4];
#pragma unroll
        for (int i = 0; i < 4; ++i) {
            a[i]  = *(const float4*)&sA[n4 + i][k0];
            xx[i] = *(const float4*)&sX[n4 + i][k0];
        }
#pragma unroll
        for (int j = 0; j < 4; ++j) {
            wl[j] = *(const float4*)&sWl[k0 + j][c4];
            wr[j] = *(const float4*)&sWr[k0 + j][c4];
        }
#pragma unroll
        for (int kk = 0; kk < 4; ++kk) {
            const float* wlk = (const float*)&wl[kk];
            const float* wrk = (const float*)&wr[kk];
#pragma unroll
            for (int i = 0; i < 4; ++i) {
                float a_ = ((const float*)&a[i])[kk];
                float x_ = ((const float*)&xx[i])[kk];
#pragma unroll
                for (int j = 0; j < 4; ++j) {
                    acc[i][j] = fmaf(a_, wlk[j], acc[i][j]);
                    acc[i][j] = fmaf(x_, wrk[j], acc[i][j]);
                }
            }
        }
    }

    const float4 bl = *(const float4*)(bias + c4);
    const float* blp = (const float*)&bl;
#pragma unroll
    for (int i = 0; i < 4; ++i) {
        int gn = nodeBase + n4 + i;
        if (gn < N) {
            float4 o;
            float* op = (float*)&o;
#pragma unroll
            for (int j = 0; j < 4; ++j) {
                float v = acc[i][j] + blp[j];
                op[j] = RELU ? fmaxf(v, 0.f) : v;
            }
            *(float4*)(out + (size_t)gn * C + c4) = o;
        }
    }
}

extern "C" void kernel_launch(void* const* d_in, const int* in_sizes, int n_in,
                              void* d_out, int out_size, void* d_ws, size_t ws_size,
                              hipStream_t stream) {
    const float* x   = (const float*)d_in[0];
    const int*   ei  = (const int*)d_in[1];
    const int*   srcI = ei;
    const int*   dstI = ei + E;
    const float* W1l = (const float*)d_in[2];
    const float* b1  = (const float*)d_in[3];
    const float* W1r = (const float*)d_in[4];
    const float* W2l = (const float*)d_in[5];
    const float* b2  = (const float*)d_in[6];
    const float* W2r = (const float*)d_in[7];
    float* out = (float*)d_out;

    int*      bcnt  = (int*)d_ws;                  // 512
    int*      bbase = bcnt + 512;                  // 512
    int*      gcur  = bbase + 512;                 // 512
    int*      deg   = gcur + 512;                  // 102400
    int*      rowp  = deg + 102400;                // 102400
    int*      csr   = rowp + 102400;               // E
    float*    agg   = (float*)(csr + E);           // N*C floats
    float*    h     = agg + (size_t)N * C;         // N*C floats
    unsigned* tmp   = (unsigned*)agg;              // 5.12 MB overlay, consumed before agg written

    hipMemsetAsync(bcnt, 0, 512 * sizeof(int), stream);

    chist_k<<<NBIN, 256, 0, stream>>>(dstI, bcnt);
    scanB_k<<<1, 512, 0, stream>>>(bcnt, bbase, gcur);
    bin_k<<<NBIN, 256, 0, stream>>>(srcI, dstI, bbase, gcur, tmp);
    bsort_k<<<NB, 256, 0, stream>>>(tmp, bbase, bcnt, rowp, deg, csr);

    const int nCombineBlocks = (N + 63) / 64;
    const int nAggBlocks = N / 4;

    agg_k<<<nAggBlocks, 256, 0, stream>>>(csr, rowp, deg, x, agg);
    combine_k<1><<<nCombineBlocks, 256, 0, stream>>>(agg, x, W1l, b1, W1r, h);

    agg_k<<<nAggBlocks, 256, 0, stream>>>(csr, rowp, deg, h, agg);
    combine_k<0><<<nCombineBlocks, 256, 0, stream>>>(agg, h, W2l, b2, W2r, out);
}

// Round 6
// 213.891 us; speedup vs baseline: 7.8246x; 1.0564x over previous
//
#include <hip/hip_runtime.h>

constexpr int N = 100000;
constexpr int E = 1280000;
constexpr int C = 64;
constexpr int NB = (N + 255) / 256;   // 391 dst-buckets of 256 nodes
constexpr int EPB = 4096;             // edges per bin_k block
constexpr int NBIN = (E + EPB - 1) / EPB;  // 313
constexpr int CAP = 4096;             // bucket capacity (avg 3274, max ~3.6k)

// ---- bf16 helpers (RNE pack, bit-trick unpack) ----
__device__ __forceinline__ unsigned bfr(float v) {
    unsigned u = __float_as_uint(v);
    return (u + 0x7fffu + ((u >> 16) & 1u)) >> 16;
}
__device__ __forceinline__ float bflo(unsigned w) { return __uint_as_float(w << 16); }
__device__ __forceinline__ float bfhi(unsigned w) { return __uint_as_float(w & 0xffff0000u); }

// ---------------- cast x -> packed bf16 rows ----------------
__global__ __launch_bounds__(256) void cast_k(const float* __restrict__ x,
                                              uint2* __restrict__ xb) {
    int i = blockIdx.x * 256 + threadIdx.x;   // one uint2 (4 channels) per thread
    if (i < N * 16) {
        float4 v = ((const float4*)x)[i];
        uint2 o;
        o.x = bfr(v.x) | (bfr(v.y) << 16);
        o.y = bfr(v.z) | (bfr(v.w) << 16);
        xb[i] = o;
    }
}

// ---------------- stage 0: coarse histogram of dst>>8 ----------------
__global__ __launch_bounds__(256) void chist_k(const int* __restrict__ dst,
                                               int* __restrict__ bcnt) {
    __shared__ int h[NB];
    int t = threadIdx.x;
    for (int i = t; i < NB; i += 256) h[i] = 0;
    __syncthreads();
    int e0 = blockIdx.x * EPB;
    int eEnd = min(e0 + EPB, E);
    for (int e = e0 + t; e < eEnd; e += 256) atomicAdd(&h[dst[e] >> 8], 1);
    __syncthreads();
    for (int i = t; i < NB; i += 256)
        if (h[i]) atomicAdd(&bcnt[i], h[i]);
}

// ---------------- stage 1: scan bucket counts -> bases; zero cursors ----------------
__global__ __launch_bounds__(512) void scanB_k(const int* __restrict__ bcnt,
                                               int* __restrict__ bbase,
                                               int* __restrict__ gcur) {
    __shared__ int s[2][512];
    int t = threadIdx.x;
    int v = (t < NB) ? bcnt[t] : 0;
    s[0][t] = v;
    __syncthreads();
    int p = 0;
    for (int off = 1; off < 512; off <<= 1) {
        int a = s[p][t] + (t >= off ? s[p][t - off] : 0);
        s[p ^ 1][t] = a;
        p ^= 1;
        __syncthreads();
    }
    if (t < NB) { bbase[t] = s[p][t] - v; gcur[t] = 0; }
}

// ---------------- stage 2: bin edges into bucket-contiguous packed runs ----------------
// packed tmp entry: (src << 8) | (dst & 255)    [src < 2^17 fits bits 8..24]
__global__ __launch_bounds__(256) void bin_k(const int* __restrict__ src,
                                             const int* __restrict__ dst,
                                             const int* __restrict__ bbase,
                                             int* __restrict__ gcur,
                                             unsigned* __restrict__ tmp) {
    __shared__ int hist[NB];
    __shared__ int start[NB];
    __shared__ int cnt2[NB];
    __shared__ int gbase[NB];
    __shared__ unsigned pk[EPB];          // 16 KB
    __shared__ unsigned short bkt[EPB];   // 8 KB
    __shared__ int sc[2][512];
    int t = threadIdx.x;
    for (int i = t; i < NB; i += 256) { hist[i] = 0; cnt2[i] = 0; }
    __syncthreads();
    int e0 = blockIdx.x * EPB;
    int eEnd = min(e0 + EPB, E);
    for (int e = e0 + t; e < eEnd; e += 256) atomicAdd(&hist[dst[e] >> 8], 1);
    __syncthreads();
    sc[0][t]       = (t < NB) ? hist[t] : 0;
    sc[0][t + 256] = (t + 256 < NB) ? hist[t + 256] : 0;
    __syncthreads();
    int p = 0;
    for (int off = 1; off < 512; off <<= 1) {
        int a = sc[p][t]       + (t >= off ? sc[p][t - off] : 0);
        int b = sc[p][t + 256] + sc[p][t + 256 - off];
        sc[p ^ 1][t] = a;
        sc[p ^ 1][t + 256] = b;
        p ^= 1;
        __syncthreads();
    }
    if (t < NB)       start[t]       = sc[p][t]       - hist[t];
    if (t + 256 < NB) start[t + 256] = sc[p][t + 256] - hist[t + 256];
    __syncthreads();
    for (int e = e0 + t; e < eEnd; e += 256) {
        int d = dst[e];
        int b = d >> 8;
        int pos = start[b] + atomicAdd(&cnt2[b], 1);
        pk[pos] = ((unsigned)src[e] << 8) | (unsigned)(d & 255);
        bkt[pos] = (unsigned short)b;
    }
    __syncthreads();
    for (int i = t; i < NB; i += 256)
        gbase[i] = hist[i] ? bbase[i] + atomicAdd(&gcur[i], hist[i]) : 0;
    __syncthreads();
    int n = eEnd - e0;
    for (int i = t; i < n; i += 256) {
        int b = bkt[i];
        tmp[gbase[b] + (i - start[b])] = pk[i];
    }
}

// ---------------- stage 3: per-bucket counting sort -> rowp/deg/csr ----------------
__global__ __launch_bounds__(256) void bsort_k(const unsigned* __restrict__ tmp,
                                               const int* __restrict__ bbase,
                                               const int* __restrict__ bcnt,
                                               int* __restrict__ rowp,
                                               int* __restrict__ deg,
                                               int* __restrict__ csr) {
    int b = blockIdx.x;
    int base = bbase[b];
    int count = bcnt[b];
    __shared__ int h[256], st[256], c2[256];
    __shared__ int sc[2][256];
    __shared__ unsigned srcA[CAP];   // 16 KB
    int t = threadIdx.x;
    h[t] = 0; c2[t] = 0;
    __syncthreads();
    for (int i = t; i < count; i += 256) atomicAdd(&h[tmp[base + i] & 255u], 1);
    __syncthreads();
    sc[0][t] = h[t];
    __syncthreads();
    int p = 0;
    for (int off = 1; off < 256; off <<= 1) {
        int a = sc[p][t] + (t >= off ? sc[p][t - off] : 0);
        sc[p ^ 1][t] = a;
        p ^= 1;
        __syncthreads();
    }
    int excl = sc[p][t] - h[t];
    st[t] = excl;
    int node = b * 256 + t;
    if (node < N) { rowp[node] = base + excl; deg[node] = h[t]; }
    __syncthreads();
    for (int i = t; i < count; i += 256) {
        unsigned pr = tmp[base + i];
        int d = (int)(pr & 255u);
        int pos = st[d] + atomicAdd(&c2[d], 1);
        srcA[pos] = pr >> 8;
    }
    __syncthreads();
    for (int i = t; i < count; i += 256) csr[base + i] = (int)srcA[i];
}

// ------- aggregation: one wave per node, 4 edge-groups x 16 lanes x 4 bf16 channels -------
__global__ __launch_bounds__(256) void agg_k(const int* __restrict__ csr,
                                             const int* __restrict__ rowp,
                                             const int* __restrict__ deg,
                                             const uint2* __restrict__ featb,
                                             float* __restrict__ agg) {
    int node = blockIdx.x * 4 + (threadIdx.x >> 6);
    int lane = threadIdx.x & 63;
    int g = lane >> 4;            // edge group 0..3
    int q = lane & 15;            // channel quad index
    int start = rowp[node];
    int d = deg[node];
    float4 acc = make_float4(0.f, 0.f, 0.f, 0.f);
    int j = g;
    for (; j + 4 < d; j += 8) {   // 8 edges in flight per wave
        int s0 = csr[start + j];
        int s1 = csr[start + j + 4];
        uint2 u0 = featb[(size_t)s0 * 16 + q];
        uint2 u1 = featb[(size_t)s1 * 16 + q];
        acc.x += bflo(u0.x) + bflo(u1.x);
        acc.y += bfhi(u0.x) + bfhi(u1.x);
        acc.z += bflo(u0.y) + bflo(u1.y);
        acc.w += bfhi(u0.y) + bfhi(u1.y);
    }
    for (; j < d; j += 4) {
        int s0 = csr[start + j];
        uint2 u0 = featb[(size_t)s0 * 16 + q];
        acc.x += bflo(u0.x); acc.y += bfhi(u0.x);
        acc.z += bflo(u0.y); acc.w += bfhi(u0.y);
    }
#pragma unroll
    for (int off = 16; off <= 32; off <<= 1) {
        acc.x += __shfl_xor(acc.x, off);
        acc.y += __shfl_xor(acc.y, off);
        acc.z += __shfl_xor(acc.z, off);
        acc.w += __shfl_xor(acc.w, off);
    }
    if (g == 0) {
        float inv = d > 0 ? 1.f / (float)d : 0.f;
        acc.x *= inv; acc.y *= inv; acc.z *= inv; acc.w *= inv;
        *(float4*)(agg + (size_t)node * C + q * 4) = acc;
    }
}

// ---------------- combine: tiled register-blocked GEMM ----------------
// RELU: apply relu.  XBF: root input is packed bf16.  OBF: write packed bf16 output.
template <int RELU, int XBF, int OBF>
__global__ __launch_bounds__(256, 2) void combine_k(
    const float* __restrict__ agg,
    const float* __restrict__ xin_f, const uint2* __restrict__ xin_b,
    const float* __restrict__ Wl, const float* __restrict__ bias,
    const float* __restrict__ Wr,
    float* __restrict__ out_f, uint2* __restrict__ out_b) {
    constexpr int PADC = C + 4;
    __shared__ float sA[64][PADC];
    __shared__ float sX[64][PADC];
    __shared__ float sWl[C][C];
    __shared__ float sWr[C][C];

    const int t = threadIdx.x;
    const int nodeBase = blockIdx.x * 64;

#pragma unroll
    for (int i = 0; i < 4; ++i) {
        int flat = (t + i * 256) * 4;
        int c = flat >> 6, k = flat & 63;
        float4 wl = *(const float4*)(Wl + flat);
        float4 wr = *(const float4*)(Wr + flat);
        sWl[k + 0][c] = wl.x; sWl[k + 1][c] = wl.y; sWl[k + 2][c] = wl.z; sWl[k + 3][c] = wl.w;
        sWr[k + 0][c] = wr.x; sWr[k + 1][c] = wr.y; sWr[k + 2][c] = wr.z; sWr[k + 3][c] = wr.w;
    }

    {
        const int f4 = (t & 15) * 4;
        const int r0 = t >> 4;
#pragma unroll
        for (int r = 0; r < 4; ++r) {
            int n = r0 + r * 16;
            int gn = nodeBase + n;
            float4 av = make_float4(0.f, 0.f, 0.f, 0.f);
            float4 xv = make_float4(0.f, 0.f, 0.f, 0.f);
            if (gn < N) {
                av = *(const float4*)(agg + (size_t)gn * C + f4);
                if (XBF) {
                    uint2 u = xin_b[(size_t)gn * 16 + (f4 >> 2)];
                    xv = make_float4(bflo(u.x), bfhi(u.x), bflo(u.y), bfhi(u.y));
                } else {
                    xv = *(const float4*)(xin_f + (size_t)gn * C + f4);
                }
            }
            *(float4*)&sA[n][f4] = av;
            *(float4*)&sX[n][f4] = xv;
        }
    }
    __syncthreads();

    const int c4 = (t & 15) * 4;
    const int n4 = (t >> 4) * 4;

    float acc[4][4];
#pragma unroll
    for (int i = 0; i < 4; ++i)
#pragma unroll
        for (int j = 0; j < 4; ++j) acc[i][j] = 0.f;

    for (int k0 = 0; k0 < C; k0 += 4) {
        float4 a[4], xx[4], wl[4], wr[4];
#pragma unroll
        for (int i = 0; i < 4; ++i) {
            a[i]  = *(const float4*)&sA[n4 + i][k0];
            xx[i] = *(const float4*)&sX[n4 + i][k0];
        }
#pragma unroll
        for (int j = 0; j < 4; ++j) {
            wl[j] = *(const float4*)&sWl[k0 + j][c4];
            wr[j] = *(const float4*)&sWr[k0 + j][c4];
        }
#pragma unroll
        for (int kk = 0; kk < 4; ++kk) {
            const float* wlk = (const float*)&wl[kk];
            const float* wrk = (const float*)&wr[kk];
#pragma unroll
            for (int i = 0; i < 4; ++i) {
                float a_ = ((const float*)&a[i])[kk];
                float x_ = ((const float*)&xx[i])[kk];
#pragma unroll
                for (int j = 0; j < 4; ++j) {
                    acc[i][j] = fmaf(a_, wlk[j], acc[i][j]);
                    acc[i][j] = fmaf(x_, wrk[j], acc[i][j]);
                }
            }
        }
    }

    const float4 bl = *(const float4*)(bias + c4);
    const float* blp = (const float*)&bl;
#pragma unroll
    for (int i = 0; i < 4; ++i) {
        int gn = nodeBase + n4 + i;
        if (gn < N) {
            float v[4];
#pragma unroll
            for (int j = 0; j < 4; ++j) {
                float w = acc[i][j] + blp[j];
                v[j] = RELU ? fmaxf(w, 0.f) : w;
            }
            if (OBF) {
                uint2 o;
                o.x = bfr(v[0]) | (bfr(v[1]) << 16);
                o.y = bfr(v[2]) | (bfr(v[3]) << 16);
                out_b[(size_t)gn * 16 + (c4 >> 2)] = o;
            } else {
                float4 o = make_float4(v[0], v[1], v[2], v[3]);
                *(float4*)(out_f + (size_t)gn * C + c4) = o;
            }
        }
    }
}

extern "C" void kernel_launch(void* const* d_in, const int* in_sizes, int n_in,
                              void* d_out, int out_size, void* d_ws, size_t ws_size,
                              hipStream_t stream) {
    const float* x   = (const float*)d_in[0];
    const int*   ei  = (const int*)d_in[1];
    const int*   srcI = ei;
    const int*   dstI = ei + E;
    const float* W1l = (const float*)d_in[2];
    const float* b1  = (const float*)d_in[3];
    const float* W1r = (const float*)d_in[4];
    const float* W2l = (const float*)d_in[5];
    const float* b2  = (const float*)d_in[6];
    const float* W2r = (const float*)d_in[7];
    float* out = (float*)d_out;

    // workspace layout (4B units)
    int*      bcnt  = (int*)d_ws;                  // 512
    int*      bbase = bcnt + 512;                  // 512
    int*      gcur  = bbase + 512;                 // 512
    int*      deg   = gcur + 512;                  // 102400
    int*      rowp  = deg + 102400;                // 102400
    int*      csr   = rowp + 102400;               // E
    float*    agg   = (float*)(csr + E);           // N*C fp32 (25.6 MB)
    uint2*    xb    = (uint2*)(agg + (size_t)N * C);   // N*16 uint2 (12.8 MB)
    uint2*    hb    = xb + (size_t)N * 16;             // N*16 uint2 (12.8 MB)
    unsigned* tmp   = (unsigned*)agg;              // 5.12 MB overlay, consumed before agg written

    hipMemsetAsync(bcnt, 0, 512 * sizeof(int), stream);

    cast_k<<<(N * 16 + 255) / 256, 256, 0, stream>>>(x, xb);
    chist_k<<<NBIN, 256, 0, stream>>>(dstI, bcnt);
    scanB_k<<<1, 512, 0, stream>>>(bcnt, bbase, gcur);
    bin_k<<<NBIN, 256, 0, stream>>>(srcI, dstI, bbase, gcur, tmp);
    bsort_k<<<NB, 256, 0, stream>>>(tmp, bbase, bcnt, rowp, deg, csr);

    const int nCombineBlocks = (N + 63) / 64;
    const int nAggBlocks = N / 4;

    // ---- layer 1 ----
    agg_k<<<nAggBlocks, 256, 0, stream>>>(csr, rowp, deg, xb, agg);
    combine_k<1, 0, 1><<<nCombineBlocks, 256, 0, stream>>>(
        agg, x, nullptr, W1l, b1, W1r, nullptr, hb);

    // ---- layer 2 ----
    agg_k<<<nAggBlocks, 256, 0, stream>>>(csr, rowp, deg, hb, agg);
    combine_k<0, 1, 0><<<nCombineBlocks, 256, 0, stream>>>(
        agg, nullptr, hb, W2l, b2, W2r, out, nullptr);
}

// Round 7
// 178.324 us; speedup vs baseline: 9.3852x; 1.1994x over previous
//
#include <hip/hip_runtime.h>

constexpr int N = 100000;
constexpr int E = 1280000;
constexpr int C = 64;
constexpr int NB = (N + 255) / 256;   // 391 dst-buckets of 256 nodes
constexpr int EPB = 4096;             // edges per bin_k block
constexpr int NBIN = (E + EPB - 1) / EPB;  // 313
constexpr int CAP = 4096;             // bucket capacity (avg 3274, max ~3.6k)

typedef __attribute__((ext_vector_type(8))) short bf16x8;
typedef __attribute__((ext_vector_type(4))) float f32x4;

// ---- bf16 helpers (RNE pack, bit-trick unpack) ----
__device__ __forceinline__ unsigned bfr(float v) {
    unsigned u = __float_as_uint(v);
    return (u + 0x7fffu + ((u >> 16) & 1u)) >> 16;
}
__device__ __forceinline__ float bflo(unsigned w) { return __uint_as_float(w << 16); }
__device__ __forceinline__ float bfhi(unsigned w) { return __uint_as_float(w & 0xffff0000u); }

// ---------------- cast x -> packed bf16 rows ----------------
__global__ __launch_bounds__(256) void cast_k(const float* __restrict__ x,
                                              uint2* __restrict__ xb) {
    int i = blockIdx.x * 256 + threadIdx.x;   // one uint2 (4 channels) per thread
    if (i < N * 16) {
        float4 v = ((const float4*)x)[i];
        uint2 o;
        o.x = bfr(v.x) | (bfr(v.y) << 16);
        o.y = bfr(v.z) | (bfr(v.w) << 16);
        xb[i] = o;
    }
}

// ---------------- cast Wl|Wr -> bf16 concat table Wb[64][128] ----------------
__global__ __launch_bounds__(256) void wcast_k(const float* __restrict__ Wl,
                                               const float* __restrict__ Wr,
                                               unsigned* __restrict__ Wb) {
    int u = blockIdx.x * 256 + threadIdx.x;   // one packed uint (2 bf16) per thread
    if (u < 64 * 64) {
        int c = u >> 5;        // 64 rows, 32 uints per half-row
        int p = u & 31;        // pair index within the 64-k half
        float2 l = *(const float2*)(Wl + c * 64 + p * 2);
        float2 r = *(const float2*)(Wr + c * 64 + p * 2);
        Wb[c * 64 + p]      = bfr(l.x) | (bfr(l.y) << 16);
        Wb[c * 64 + 32 + p] = bfr(r.x) | (bfr(r.y) << 16);
    }
}

// ---------------- stage 0: coarse histogram of dst>>8 ----------------
__global__ __launch_bounds__(256) void chist_k(const int* __restrict__ dst,
                                               int* __restrict__ bcnt) {
    __shared__ int h[NB];
    int t = threadIdx.x;
    for (int i = t; i < NB; i += 256) h[i] = 0;
    __syncthreads();
    int e0 = blockIdx.x * EPB;
    int eEnd = min(e0 + EPB, E);
    for (int e = e0 + t; e < eEnd; e += 256) atomicAdd(&h[dst[e] >> 8], 1);
    __syncthreads();
    for (int i = t; i < NB; i += 256)
        if (h[i]) atomicAdd(&bcnt[i], h[i]);
}

// ---------------- stage 1: scan bucket counts -> bases; zero cursors ----------------
__global__ __launch_bounds__(512) void scanB_k(const int* __restrict__ bcnt,
                                               int* __restrict__ bbase,
                                               int* __restrict__ gcur) {
    __shared__ int s[2][512];
    int t = threadIdx.x;
    int v = (t < NB) ? bcnt[t] : 0;
    s[0][t] = v;
    __syncthreads();
    int p = 0;
    for (int off = 1; off < 512; off <<= 1) {
        int a = s[p][t] + (t >= off ? s[p][t - off] : 0);
        s[p ^ 1][t] = a;
        p ^= 1;
        __syncthreads();
    }
    if (t < NB) { bbase[t] = s[p][t] - v; gcur[t] = 0; }
}

// ---------------- stage 2: bin edges into bucket-contiguous packed runs ----------------
// packed tmp entry: (src << 8) | (dst & 255)    [src < 2^17 fits bits 8..24]
__global__ __launch_bounds__(256) void bin_k(const int* __restrict__ src,
                                             const int* __restrict__ dst,
                                             const int* __restrict__ bbase,
                                             int* __restrict__ gcur,
                                             unsigned* __restrict__ tmp) {
    __shared__ int hist[NB];
    __shared__ int start[NB];
    __shared__ int cnt2[NB];
    __shared__ int gbase[NB];
    __shared__ unsigned pk[EPB];          // 16 KB
    __shared__ unsigned short bkt[EPB];   // 8 KB
    __shared__ int sc[2][512];
    int t = threadIdx.x;
    for (int i = t; i < NB; i += 256) { hist[i] = 0; cnt2[i] = 0; }
    __syncthreads();
    int e0 = blockIdx.x * EPB;
    int eEnd = min(e0 + EPB, E);
    for (int e = e0 + t; e < eEnd; e += 256) atomicAdd(&hist[dst[e] >> 8], 1);
    __syncthreads();
    sc[0][t]       = (t < NB) ? hist[t] : 0;
    sc[0][t + 256] = (t + 256 < NB) ? hist[t + 256] : 0;
    __syncthreads();
    int p = 0;
    for (int off = 1; off < 512; off <<= 1) {
        int a = sc[p][t]       + (t >= off ? sc[p][t - off] : 0);
        int b = sc[p][t + 256] + sc[p][t + 256 - off];
        sc[p ^ 1][t] = a;
        sc[p ^ 1][t + 256] = b;
        p ^= 1;
        __syncthreads();
    }
    if (t < NB)       start[t]       = sc[p][t]       - hist[t];
    if (t + 256 < NB) start[t + 256] = sc[p][t + 256] - hist[t + 256];
    __syncthreads();
    for (int e = e0 + t; e < eEnd; e += 256) {
        int d = dst[e];
        int b = d >> 8;
        int pos = start[b] + atomicAdd(&cnt2[b], 1);
        pk[pos] = ((unsigned)src[e] << 8) | (unsigned)(d & 255);
        bkt[pos] = (unsigned short)b;
    }
    __syncthreads();
    for (int i = t; i < NB; i += 256)
        gbase[i] = hist[i] ? bbase[i] + atomicAdd(&gcur[i], hist[i]) : 0;
    __syncthreads();
    int n = eEnd - e0;
    for (int i = t; i < n; i += 256) {
        int b = bkt[i];
        tmp[gbase[b] + (i - start[b])] = pk[i];
    }
}

// ---------------- stage 3: per-bucket counting sort -> rowp/deg/csr ----------------
__global__ __launch_bounds__(256) void bsort_k(const unsigned* __restrict__ tmp,
                                               const int* __restrict__ bbase,
                                               const int* __restrict__ bcnt,
                                               int* __restrict__ rowp,
                                               int* __restrict__ deg,
                                               int* __restrict__ csr) {
    int b = blockIdx.x;
    int base = bbase[b];
    int count = bcnt[b];
    __shared__ int h[256], st[256], c2[256];
    __shared__ int sc[2][256];
    __shared__ unsigned srcA[CAP];   // 16 KB
    int t = threadIdx.x;
    h[t] = 0; c2[t] = 0;
    __syncthreads();
    for (int i = t; i < count; i += 256) atomicAdd(&h[tmp[base + i] & 255u], 1);
    __syncthreads();
    sc[0][t] = h[t];
    __syncthreads();
    int p = 0;
    for (int off = 1; off < 256; off <<= 1) {
        int a = sc[p][t] + (t >= off ? sc[p][t - off] : 0);
        sc[p ^ 1][t] = a;
        p ^= 1;
        __syncthreads();
    }
    int excl = sc[p][t] - h[t];
    st[t] = excl;
    int node = b * 256 + t;
    if (node < N) { rowp[node] = base + excl; deg[node] = h[t]; }
    __syncthreads();
    for (int i = t; i < count; i += 256) {
        unsigned pr = tmp[base + i];
        int d = (int)(pr & 255u);
        int pos = st[d] + atomicAdd(&c2[d], 1);
        srcA[pos] = pr >> 8;
    }
    __syncthreads();
    for (int i = t; i < count; i += 256) csr[base + i] = (int)srcA[i];
}

// ------- aggregation: one wave per node, 4 edge-groups x 16 lanes x 4 bf16 channels -------
// output: mean, packed bf16 row-major [N][64]
__global__ __launch_bounds__(256) void agg_k(const int* __restrict__ csr,
                                             const int* __restrict__ rowp,
                                             const int* __restrict__ deg,
                                             const uint2* __restrict__ featb,
                                             uint2* __restrict__ aggb) {
    int node = blockIdx.x * 4 + (threadIdx.x >> 6);
    int lane = threadIdx.x & 63;
    int g = lane >> 4;            // edge group 0..3
    int q = lane & 15;            // channel quad index
    int start = rowp[node];
    int d = deg[node];
    float4 acc = make_float4(0.f, 0.f, 0.f, 0.f);
    int j = g;
    for (; j + 4 < d; j += 8) {   // 8 edges in flight per wave
        int s0 = csr[start + j];
        int s1 = csr[start + j + 4];
        uint2 u0 = featb[(size_t)s0 * 16 + q];
        uint2 u1 = featb[(size_t)s1 * 16 + q];
        acc.x += bflo(u0.x) + bflo(u1.x);
        acc.y += bfhi(u0.x) + bfhi(u1.x);
        acc.z += bflo(u0.y) + bflo(u1.y);
        acc.w += bfhi(u0.y) + bfhi(u1.y);
    }
    for (; j < d; j += 4) {
        int s0 = csr[start + j];
        uint2 u0 = featb[(size_t)s0 * 16 + q];
        acc.x += bflo(u0.x); acc.y += bfhi(u0.x);
        acc.z += bflo(u0.y); acc.w += bfhi(u0.y);
    }
#pragma unroll
    for (int off = 16; off <= 32; off <<= 1) {
        acc.x += __shfl_xor(acc.x, off);
        acc.y += __shfl_xor(acc.y, off);
        acc.z += __shfl_xor(acc.z, off);
        acc.w += __shfl_xor(acc.w, off);
    }
    if (g == 0) {
        float inv = d > 0 ? 1.f / (float)d : 0.f;
        uint2 o;
        o.x = bfr(acc.x * inv) | (bfr(acc.y * inv) << 16);
        o.y = bfr(acc.z * inv) | (bfr(acc.w * inv) << 16);
        aggb[(size_t)node * 16 + q] = o;
    }
}

// ---------------- combine via MFMA: out = [agg|x] (K=128) * Wb^T + bias ----------------
// one wave per 16-node tile; 4 col-tiles x 4 K-chunks = 16 mfma_16x16x32_bf16.
// A-frag: row = lane&15, k = (lane>>4)*8 + j (16B contiguous global load).
// B-frag: col = lane&15, k = (lane>>4)*8 + j  -> Wb[col][k] 16B contiguous.
// C/D: col = lane&15, row = (lane>>4)*4 + reg  [verified mapping].
template <int RELU, int OBF>
__global__ __launch_bounds__(256) void combine_mfma_k(
    const unsigned short* __restrict__ Ab,   // [N][64] bf16 agg
    const unsigned short* __restrict__ Xb,   // [N][64] bf16 root
    const unsigned short* __restrict__ Wb,   // [64][128] bf16 (Wl|Wr rows)
    const float* __restrict__ bias,
    float* __restrict__ outF, unsigned short* __restrict__ outB) {
    int wave = threadIdx.x >> 6;
    int lane = threadIdx.x & 63;
    int row0 = (blockIdx.x * 4 + wave) * 16;   // 16-node tile base
    if (row0 >= N) return;                      // tail waves (N = 16*6250 exact)
    int g = lane >> 4;
    int r = lane & 15;
    int node = row0 + r;

    const unsigned short* arow = Ab + (size_t)node * 64 + g * 8;
    const unsigned short* xrow = Xb + (size_t)node * 64 + g * 8;
    bf16x8 a[4];
    a[0] = *(const bf16x8*)(const void*)(arow);
    a[1] = *(const bf16x8*)(const void*)(arow + 32);
    a[2] = *(const bf16x8*)(const void*)(xrow);
    a[3] = *(const bf16x8*)(const void*)(xrow + 32);

#pragma unroll
    for (int ct = 0; ct < 4; ++ct) {
        int c = ct * 16 + r;
        const unsigned short* wrow = Wb + (size_t)c * 128 + g * 8;
        f32x4 acc = {0.f, 0.f, 0.f, 0.f};
#pragma unroll
        for (int kc = 0; kc < 4; ++kc) {
            bf16x8 b = *(const bf16x8*)(const void*)(wrow + kc * 32);
            acc = __builtin_amdgcn_mfma_f32_16x16x32_bf16(a[kc], b, acc, 0, 0, 0);
        }
        float bs = bias[c];
#pragma unroll
        for (int rr = 0; rr < 4; ++rr) {
            int orow = row0 + g * 4 + rr;
            float v = acc[rr] + bs;
            if (RELU) v = fmaxf(v, 0.f);
            if (OBF) {
                float v1 = __shfl_xor(v, 1);    // neighbor column's value
                if ((lane & 1) == 0) {
                    unsigned u = bfr(v) | (bfr(v1) << 16);
                    *(unsigned*)(void*)(outB + (size_t)orow * 64 + c) = u;
                }
            } else {
                outF[(size_t)orow * 64 + c] = v;
            }
        }
    }
}

extern "C" void kernel_launch(void* const* d_in, const int* in_sizes, int n_in,
                              void* d_out, int out_size, void* d_ws, size_t ws_size,
                              hipStream_t stream) {
    const float* x   = (const float*)d_in[0];
    const int*   ei  = (const int*)d_in[1];
    const int*   srcI = ei;
    const int*   dstI = ei + E;
    const float* W1l = (const float*)d_in[2];
    const float* b1  = (const float*)d_in[3];
    const float* W1r = (const float*)d_in[4];
    const float* W2l = (const float*)d_in[5];
    const float* b2  = (const float*)d_in[6];
    const float* W2r = (const float*)d_in[7];
    float* out = (float*)d_out;

    // workspace layout (4B units)
    int*            bcnt  = (int*)d_ws;                    // 512
    int*            bbase = bcnt + 512;                    // 512
    int*            gcur  = bbase + 512;                   // 512
    int*            deg   = gcur + 512;                    // 102400
    int*            rowp  = deg + 102400;                  // 102400
    int*            csr   = rowp + 102400;                 // E
    unsigned short* aggb  = (unsigned short*)(csr + E);    // N*64 bf16 (12.8 MB)
    unsigned short* xb    = aggb + (size_t)N * 64;         // N*64 bf16
    unsigned short* hb    = xb + (size_t)N * 64;           // N*64 bf16
    unsigned*       Wb1   = (unsigned*)(hb + (size_t)N * 64);  // 64*64 uints (16 KB)
    unsigned*       Wb2   = Wb1 + 64 * 64;                     // 16 KB
    unsigned*       tmp   = (unsigned*)aggb;               // 5.12 MB overlay, consumed before aggb written

    hipMemsetAsync(bcnt, 0, 512 * sizeof(int), stream);

    cast_k<<<(N * 16 + 255) / 256, 256, 0, stream>>>(x, (uint2*)xb);
    wcast_k<<<16, 256, 0, stream>>>(W1l, W1r, Wb1);
    wcast_k<<<16, 256, 0, stream>>>(W2l, W2r, Wb2);
    chist_k<<<NBIN, 256, 0, stream>>>(dstI, bcnt);
    scanB_k<<<1, 512, 0, stream>>>(bcnt, bbase, gcur);
    bin_k<<<NBIN, 256, 0, stream>>>(srcI, dstI, bbase, gcur, tmp);
    bsort_k<<<NB, 256, 0, stream>>>(tmp, bbase, bcnt, rowp, deg, csr);

    const int nAggBlocks = N / 4;
    const int nMfmaBlocks = (N / 16 + 3) / 4;   // 1563

    // ---- layer 1 ----
    agg_k<<<nAggBlocks, 256, 0, stream>>>(csr, rowp, deg, (const uint2*)xb, (uint2*)aggb);
    combine_mfma_k<1, 1><<<nMfmaBlocks, 256, 0, stream>>>(
        aggb, xb, (const unsigned short*)Wb1, b1, nullptr, hb);

    // ---- layer 2 ----
    agg_k<<<nAggBlocks, 256, 0, stream>>>(csr, rowp, deg, (const uint2*)hb, (uint2*)aggb);
    combine_mfma_k<0, 0><<<nMfmaBlocks, 256, 0, stream>>>(
        aggb, hb, (const unsigned short*)Wb2, b2, out, nullptr);
}